// Round 3
// baseline (215.927 us; speedup 1.0000x reference)
//
#include <hip/hip_runtime.h>
#include <hip/hip_bf16.h>

#define N_SIG 2048
#define BLK   256

// ---------------- Kernel 1: per-signal derived quantities ----------------
__global__ void derive_k(const float* __restrict__ p, float* __restrict__ dv) {
    int j = blockIdx.x * blockDim.x + threadIdx.x;
    if (j >= N_SIG) return;
    const float* pj = p + j * 15;
    float p0 = pj[0], p1 = pj[1], p2 = pj[2];
    float p3 = pj[3], p4 = pj[4], p5 = pj[5], p7 = pj[7];
    float m1 = p0 * 95.f + 5.f, m2 = p1 * 95.f + 5.f;
    float mc = powf(m1 * m2, 0.6f) / powf(m1 + m2, 0.2f);
    float fisco = 220.f / (m1 + m2);
    float dist = p2 * 2950.f + 50.f;
    float4* o = (float4*)(dv + j * 8);
    o[0] = make_float4(p5, p3, p4, mc);       // t, ra, dec, mc
    o[1] = make_float4(fisco, dist, p7, 0.f); // fisco, dist, psi, pad
}

// ---------------- Kernel 2: one block per row i ----------------
__global__ __launch_bounds__(BLK) void row_k(
    const float* __restrict__ dv,
    const float* __restrict__ iw1, const float* __restrict__ ib1,
    const float* __restrict__ ig1, const float* __restrict__ ibt1,
    const float* __restrict__ iw2, const float* __restrict__ ib2,
    const float* __restrict__ ow1, const float* __restrict__ ob1,
    const float* __restrict__ og1, const float* __restrict__ obt1,
    const float* __restrict__ ow2, const float* __restrict__ ob2,
    float* __restrict__ out)
{
    __shared__ __align__(16) float sW1[128];                  // iw1 [16][8]
    __shared__ __align__(16) float sB1[16], sG1[16], sBt1[16], sW2[16];
    __shared__ float sB2;
    __shared__ __align__(16) float sOW1[256];                 // ow1 [32][8]
    __shared__ __align__(16) float sOW2[512];                 // ow2 [16][32]
    __shared__ float sOB1[32], sOG1[32], sOBt1[32], sOB2[16];
    __shared__ float mred[4], lred[4], wred[4][8];
    __shared__ float h2s[32];

    const int tid = threadIdx.x;
    const int i   = blockIdx.x;

    // ---- cooperative weight load (f32 -> LDS) ----
    if (tid < 128) sW1[tid] = iw1[tid];
    if (tid >= 128 && tid < 144) {
        int k = tid - 128;
        sB1[k] = ib1[k]; sG1[k] = ig1[k]; sBt1[k] = ibt1[k]; sW2[k] = iw2[k];
    }
    if (tid == 144) sB2 = ib2[0];
    sOW1[tid] = ow1[tid];
    sOW2[tid] = ow2[tid];
    sOW2[tid + 256] = ow2[tid + 256];
    if (tid >= 160 && tid < 192) {
        int k = tid - 160;
        sOB1[k] = ob1[k]; sOG1[k] = og1[k]; sOBt1[k] = obt1[k];
    }
    if (tid >= 192 && tid < 208) sOB2[tid - 192] = ob2[tid - 192];
    __syncthreads();

    // ---- row-invariant derived values ----
    const float4 di0 = *(const float4*)(dv + i * 8);
    const float4 di1 = *(const float4*)(dv + i * 8 + 4);
    const float ti = di0.x, rai = di0.y, deci = di0.z, mci = di0.w;
    const float fi = di1.x, disti = di1.y, psii = di1.z;

    float m_t = -1e30f, l_t = 0.f;
    float w_t[8];
    #pragma unroll
    for (int f = 0; f < 8; f++) w_t[f] = 0.f;

    const float inv_sqrt2 = 0.70710678118654752f;

    for (int j = tid; j < N_SIG; j += BLK) {
        if (j == i) continue;
        const float4 dj0 = *(const float4*)(dv + j * 8);
        const float4 dj1 = *(const float4*)(dv + j * 8 + 4);

        const float dt   = fabsf(ti - dj0.x);
        const float dra  = fabsf(rai - dj0.y);
        const float ddec = fabsf(deci - dj0.z);
        const float sky  = sqrtf(dra * dra + ddec * ddec);
        const float msim = 1.f / (1.f + fabsf(mci - dj0.w) * (1.f / 30.f));
        const float fov  = __expf(-fabsf(fi - dj1.x) * 0.01f);
        const float drat = fminf(disti, dj1.y) / fmaxf(disti, dj1.y);
        const float dpsi = fabsf(psii - dj1.z);

        float f[8] = {dt, sky, msim, fov, drat, dpsi, dra, ddec};

        // 8 -> 16 GEMV (weights broadcast from LDS as float4)
        float z[16];
        #pragma unroll
        for (int h = 0; h < 16; h++) {
            const float4 wa = *(const float4*)(sW1 + h * 8);
            const float4 wb = *(const float4*)(sW1 + h * 8 + 4);
            z[h] = sB1[h] + wa.x * f[0] + wa.y * f[1] + wa.z * f[2] + wa.w * f[3]
                          + wb.x * f[4] + wb.y * f[5] + wb.z * f[6] + wb.w * f[7];
        }
        // LayerNorm(16)
        float mu = 0.f;
        #pragma unroll
        for (int h = 0; h < 16; h++) mu += z[h];
        mu *= (1.f / 16.f);
        float var = 0.f;
        #pragma unroll
        for (int h = 0; h < 16; h++) { const float d = z[h] - mu; var += d * d; }
        var *= (1.f / 16.f);
        const float inv = rsqrtf(var + 1e-5f);
        // GELU(erf) + dot with iw2
        float logit = sB2;
        #pragma unroll
        for (int h = 0; h < 16; h++) {
            const float y = (z[h] - mu) * inv * sG1[h] + sBt1[h];
            const float g = 0.5f * y * (1.f + erff(y * inv_sqrt2));
            logit += g * sW2[h];
        }
        // online softmax update
        if (logit > m_t) {
            const float s = __expf(m_t - logit);
            l_t = l_t * s + 1.f;
            #pragma unroll
            for (int f2 = 0; f2 < 8; f2++) w_t[f2] = w_t[f2] * s + f[f2];
            m_t = logit;
        } else {
            const float e = __expf(logit - m_t);
            l_t += e;
            #pragma unroll
            for (int f2 = 0; f2 < 8; f2++) w_t[f2] += e * f[f2];
        }
    }

    // ---- block softmax reduction ----
    float m_w = m_t;
    #pragma unroll
    for (int off = 32; off > 0; off >>= 1) m_w = fmaxf(m_w, __shfl_xor(m_w, off));
    const int wid = tid >> 6, lane = tid & 63;
    if (lane == 0) mred[wid] = m_w;
    __syncthreads();
    const float M = fmaxf(fmaxf(mred[0], mred[1]), fmaxf(mred[2], mred[3]));
    const float s = __expf(m_t - M);
    l_t *= s;
    #pragma unroll
    for (int f = 0; f < 8; f++) w_t[f] *= s;
    #pragma unroll
    for (int off = 32; off > 0; off >>= 1) {
        l_t += __shfl_xor(l_t, off);
        #pragma unroll
        for (int f = 0; f < 8; f++) w_t[f] += __shfl_xor(w_t[f], off);
    }
    if (lane == 0) {
        lred[wid] = l_t;
        #pragma unroll
        for (int f = 0; f < 8; f++) wred[wid][f] = w_t[f];
    }
    __syncthreads();

    // ---- overlap net: lanes 0..31 of wave 0 ----
    if (tid < 32) {
        const float L = lred[0] + lred[1] + lred[2] + lred[3];
        const float invL = 1.f / L;
        float z2 = sOB1[tid];
        #pragma unroll
        for (int f = 0; f < 8; f++) {
            const float W = (wred[0][f] + wred[1][f] + wred[2][f] + wred[3][f]) * invL;
            z2 += sOW1[tid * 8 + f] * W;
        }
        // LN over the 32 lanes
        float mu = z2;
        #pragma unroll
        for (int off = 16; off > 0; off >>= 1) mu += __shfl_xor(mu, off);
        mu *= (1.f / 32.f);
        const float d = z2 - mu;
        float var = d * d;
        #pragma unroll
        for (int off = 16; off > 0; off >>= 1) var += __shfl_xor(var, off);
        var *= (1.f / 32.f);
        const float y = d * rsqrtf(var + 1e-5f) * sOG1[tid] + sOBt1[tid];
        h2s[tid] = 0.5f * y * (1.f + erff(y * inv_sqrt2));
    }
    __syncthreads();
    if (tid < 16) {
        float o = sOB2[tid];
        #pragma unroll
        for (int k = 0; k < 32; k++) o += sOW2[tid * 32 + k] * h2s[k];
        out[i * 16 + tid] = o;   // f32 output per reference dtype
    }
}

extern "C" void kernel_launch(void* const* d_in, const int* in_sizes, int n_in,
                              void* d_out, int out_size, void* d_ws, size_t ws_size,
                              hipStream_t stream) {
    const float* p    = (const float*)d_in[0];
    const float* iw1  = (const float*)d_in[1];
    const float* ib1  = (const float*)d_in[2];
    const float* ig1  = (const float*)d_in[3];
    const float* ibt1 = (const float*)d_in[4];
    const float* iw2  = (const float*)d_in[5];
    const float* ib2  = (const float*)d_in[6];
    const float* ow1  = (const float*)d_in[7];
    const float* ob1  = (const float*)d_in[8];
    const float* og1  = (const float*)d_in[9];
    const float* obt1 = (const float*)d_in[10];
    const float* ow2  = (const float*)d_in[11];
    const float* ob2  = (const float*)d_in[12];
    float* dv = (float*)d_ws;

    derive_k<<<N_SIG / BLK, BLK, 0, stream>>>(p, dv);
    row_k<<<N_SIG, BLK, 0, stream>>>(dv, iw1, ib1, ig1, ibt1, iw2, ib2,
                                     ow1, ob1, og1, obt1, ow2, ob2,
                                     (float*)d_out);
}

// Round 4
// 165.050 us; speedup vs baseline: 1.3083x; 1.3083x over previous
//
#include <hip/hip_runtime.h>

#define N_SIG 2048
#define BLK   256

__device__ __forceinline__ float frcp(float x) { return __builtin_amdgcn_rcpf(x); }

// erf(y / sqrt(2)) — Abramowitz–Stegun 7.1.26 with sqrt2 folded in, |err| < 1.5e-7
__device__ __forceinline__ float erf_div_sqrt2(float y) {
    const float ay = fabsf(y);
    const float t  = frcp(fmaf(0.23164454f, ay, 1.f));   // p/sqrt2, p = 0.3275911
    const float p  = t * fmaf(t, fmaf(t, fmaf(t, fmaf(t, 1.061405429f, -1.453152027f),
                                              1.421413741f), -0.284496736f), 0.254829592f);
    const float e  = __expf(-0.5f * ay * ay);            // exp(-(y/sqrt2)^2)
    return copysignf(fmaf(-p, e, 1.f), y);
}

// ---------------- Kernel 1: per-signal derived quantities ----------------
__global__ void derive_k(const float* __restrict__ p, float* __restrict__ dv) {
    int j = blockIdx.x * blockDim.x + threadIdx.x;
    if (j >= N_SIG) return;
    const float* pj = p + j * 15;
    float p0 = pj[0], p1 = pj[1], p2 = pj[2];
    float p3 = pj[3], p4 = pj[4], p5 = pj[5], p7 = pj[7];
    float m1 = p0 * 95.f + 5.f, m2 = p1 * 95.f + 5.f;
    float mc = powf(m1 * m2, 0.6f) / powf(m1 + m2, 0.2f);
    float fisco = 220.f / (m1 + m2);
    float dist = p2 * 2950.f + 50.f;
    float4* o = (float4*)(dv + j * 8);
    o[0] = make_float4(p5, p3, p4, mc);       // t, ra, dec, mc
    o[1] = make_float4(fisco, dist, p7, 0.f); // fisco, dist, psi, pad
}

// ---------------- Kernel 2: one block per row i ----------------
__global__ __launch_bounds__(BLK) void row_k(
    const float* __restrict__ dv,
    const float* __restrict__ iw1, const float* __restrict__ ib1,
    const float* __restrict__ ig1, const float* __restrict__ ibt1,
    const float* __restrict__ iw2, const float* __restrict__ ib2,
    const float* __restrict__ ow1, const float* __restrict__ ob1,
    const float* __restrict__ og1, const float* __restrict__ obt1,
    const float* __restrict__ ow2, const float* __restrict__ ob2,
    float* __restrict__ out)
{
    __shared__ __align__(16) float sW1[128];   // iw1 [16][8]
    __shared__ __align__(16) float sEC[64];    // per-h (b1, g1, bt1, 0.5*w2)
    __shared__ __align__(16) float sOW1[256];  // ow1 [32][8]
    __shared__ __align__(16) float sOW2[512];  // ow2 [16][32]
    __shared__ float sOB1[32], sOG1[32], sOBt1[32], sOB2[16];
    __shared__ float lred[4], wred[4][8];
    __shared__ float h2s[32];

    const int tid = threadIdx.x;
    const int i   = blockIdx.x;

    // ---- cooperative constant staging ----
    if (tid < 128) sW1[tid] = iw1[tid];
    if (tid < 16) {
        sEC[tid * 4 + 0] = ib1[tid];
        sEC[tid * 4 + 1] = ig1[tid];
        sEC[tid * 4 + 2] = ibt1[tid];
        sEC[tid * 4 + 3] = 0.5f * iw2[tid];
    }
    sOW1[tid] = ow1[tid];
    sOW2[tid] = ow2[tid];
    sOW2[tid + 256] = ow2[tid + 256];
    if (tid >= 160 && tid < 192) {
        int k = tid - 160;
        sOB1[k] = ob1[k]; sOG1[k] = og1[k]; sOBt1[k] = obt1[k];
    }
    if (tid >= 192 && tid < 208) sOB2[tid - 192] = ob2[tid - 192];
    __syncthreads();

    // epilogue scalars -> registers (loop-invariant, 16 float4)
    float4 ec[16];
    #pragma unroll
    for (int h = 0; h < 16; h++) ec[h] = *(const float4*)(sEC + h * 4);

    // row-invariant derived values
    const float4 di0 = *(const float4*)(dv + i * 8);
    const float4 di1 = *(const float4*)(dv + i * 8 + 4);
    const float ti = di0.x, rai = di0.y, deci = di0.z, mci = di0.w;
    const float fi = di1.x, disti = di1.y, psii = di1.z;

    float l_t = 0.f;
    float w_t[8];
    #pragma unroll
    for (int f = 0; f < 8; f++) w_t[f] = 0.f;

    const float4* dv4 = (const float4*)dv;
    const float4* sW4 = (const float4*)sW1;

    #pragma unroll 1
    for (int k = 0; k < 4; k++) {
        const int j0 = (k << 8) + tid;
        const int j1 = j0 + 1024;
        const float4 a0 = dv4[j0 * 2], a1 = dv4[j0 * 2 + 1];
        const float4 b0 = dv4[j1 * 2], b1 = dv4[j1 * 2 + 1];

        // ---- pairwise features (branchless, rcp/sqrt intrinsics) ----
        const float draA  = fabsf(rai - a0.y), ddecA = fabsf(deci - a0.z);
        const float draB  = fabsf(rai - b0.y), ddecB = fabsf(deci - b0.z);
        float fA[8], fB[8];
        fA[0] = fabsf(ti - a0.x);
        fA[1] = __builtin_amdgcn_sqrtf(fmaf(draA, draA, ddecA * ddecA));
        fA[2] = frcp(fmaf(fabsf(mci - a0.w), 0.033333333f, 1.f));
        fA[3] = __expf(fabsf(fi - a1.x) * -0.01f);
        fA[4] = fminf(disti, a1.y) * frcp(fmaxf(disti, a1.y));
        fA[5] = fabsf(psii - a1.z);
        fA[6] = draA; fA[7] = ddecA;
        fB[0] = fabsf(ti - b0.x);
        fB[1] = __builtin_amdgcn_sqrtf(fmaf(draB, draB, ddecB * ddecB));
        fB[2] = frcp(fmaf(fabsf(mci - b0.w), 0.033333333f, 1.f));
        fB[3] = __expf(fabsf(fi - b1.x) * -0.01f);
        fB[4] = fminf(disti, b1.y) * frcp(fmaxf(disti, b1.y));
        fB[5] = fabsf(psii - b1.z);
        fB[6] = draB; fB[7] = ddecB;

        // ---- 8->16 GEMV for both pairs, weights read once; fused moments ----
        float zA[16], zB[16];
        float s1A = 0.f, s2A = 0.f, s1B = 0.f, s2B = 0.f;
        #pragma unroll
        for (int h = 0; h < 16; h++) {
            const float4 w0 = sW4[h * 2];
            const float4 w1 = sW4[h * 2 + 1];
            float za = ec[h].x;
            za = fmaf(w0.x, fA[0], za); za = fmaf(w0.y, fA[1], za);
            za = fmaf(w0.z, fA[2], za); za = fmaf(w0.w, fA[3], za);
            za = fmaf(w1.x, fA[4], za); za = fmaf(w1.y, fA[5], za);
            za = fmaf(w1.z, fA[6], za); za = fmaf(w1.w, fA[7], za);
            float zb = ec[h].x;
            zb = fmaf(w0.x, fB[0], zb); zb = fmaf(w0.y, fB[1], zb);
            zb = fmaf(w0.z, fB[2], zb); zb = fmaf(w0.w, fB[3], zb);
            zb = fmaf(w1.x, fB[4], zb); zb = fmaf(w1.y, fB[5], zb);
            zb = fmaf(w1.z, fB[6], zb); zb = fmaf(w1.w, fB[7], zb);
            zA[h] = za; zB[h] = zb;
            s1A += za; s2A = fmaf(za, za, s2A);
            s1B += zb; s2B = fmaf(zb, zb, s2B);
        }
        // ---- LayerNorm stats (single pass: var = E[z^2] - mu^2) ----
        const float muA  = s1A * 0.0625f;
        const float varA = fmaf(-muA, muA, s2A * 0.0625f);
        const float invA = __builtin_amdgcn_rsqf(varA + 1e-5f);
        const float muB  = s1B * 0.0625f;
        const float varB = fmaf(-muB, muB, s2B * 0.0625f);
        const float invB = __builtin_amdgcn_rsqf(varB + 1e-5f);

        // ---- GELU(erf) + dot(iw2) ----
        float logitA = 0.f, logitB = 0.f;
        #pragma unroll
        for (int h = 0; h < 16; h++) {
            const float4 c = ec[h];  // (b, g, bt, 0.5*w2)
            const float yA = fmaf((zA[h] - muA) * invA, c.y, c.z);
            const float yB = fmaf((zB[h] - muB) * invB, c.y, c.z);
            logitA = fmaf(yA * c.w, 1.f + erf_div_sqrt2(yA), logitA);
            logitB = fmaf(yB * c.w, 1.f + erf_div_sqrt2(yB), logitB);
        }
        // +ib2 is uniform across j -> softmax-invariant, dropped.
        // |logit| <= ~16 so exp() is safe without max subtraction.
        const float eA = (j0 == i) ? 0.f : __expf(logitA);
        const float eB = (j1 == i) ? 0.f : __expf(logitB);
        l_t += eA + eB;
        #pragma unroll
        for (int f = 0; f < 8; f++) w_t[f] = fmaf(eA, fA[f], fmaf(eB, fB[f], w_t[f]));
    }

    // ---- block reduction (sums only) ----
    #pragma unroll
    for (int off = 32; off > 0; off >>= 1) {
        l_t += __shfl_xor(l_t, off);
        #pragma unroll
        for (int f = 0; f < 8; f++) w_t[f] += __shfl_xor(w_t[f], off);
    }
    const int wid = tid >> 6;
    if ((tid & 63) == 0) {
        lred[wid] = l_t;
        #pragma unroll
        for (int f = 0; f < 8; f++) wred[wid][f] = w_t[f];
    }
    __syncthreads();

    // ---- overlap net: lanes 0..31 of wave 0 ----
    if (tid < 32) {
        const float L = lred[0] + lred[1] + lred[2] + lred[3];
        const float invL = frcp(L);
        float z2 = sOB1[tid];
        #pragma unroll
        for (int f = 0; f < 8; f++) {
            const float W = (wred[0][f] + wred[1][f] + wred[2][f] + wred[3][f]) * invL;
            z2 = fmaf(sOW1[tid * 8 + f], W, z2);
        }
        float mu = z2;
        #pragma unroll
        for (int off = 16; off > 0; off >>= 1) mu += __shfl_xor(mu, off);
        mu *= (1.f / 32.f);
        const float d = z2 - mu;
        float var = d * d;
        #pragma unroll
        for (int off = 16; off > 0; off >>= 1) var += __shfl_xor(var, off);
        var *= (1.f / 32.f);
        const float y = d * __builtin_amdgcn_rsqf(var + 1e-5f) * sOG1[tid] + sOBt1[tid];
        h2s[tid] = 0.5f * y * (1.f + erf_div_sqrt2(y));
    }
    __syncthreads();
    if (tid < 16) {
        float o = sOB2[tid];
        #pragma unroll
        for (int k = 0; k < 32; k++) o = fmaf(sOW2[tid * 32 + k], h2s[k], o);
        out[i * 16 + tid] = o;
    }
}

extern "C" void kernel_launch(void* const* d_in, const int* in_sizes, int n_in,
                              void* d_out, int out_size, void* d_ws, size_t ws_size,
                              hipStream_t stream) {
    const float* p    = (const float*)d_in[0];
    const float* iw1  = (const float*)d_in[1];
    const float* ib1  = (const float*)d_in[2];
    const float* ig1  = (const float*)d_in[3];
    const float* ibt1 = (const float*)d_in[4];
    const float* iw2  = (const float*)d_in[5];
    const float* ib2  = (const float*)d_in[6];
    const float* ow1  = (const float*)d_in[7];
    const float* ob1  = (const float*)d_in[8];
    const float* og1  = (const float*)d_in[9];
    const float* obt1 = (const float*)d_in[10];
    const float* ow2  = (const float*)d_in[11];
    const float* ob2  = (const float*)d_in[12];
    float* dv = (float*)d_ws;

    derive_k<<<N_SIG / BLK, BLK, 0, stream>>>(p, dv);
    row_k<<<N_SIG, BLK, 0, stream>>>(dv, iw1, ib1, ig1, ibt1, iw2, ib2,
                                     ow1, ob1, og1, obt1, ow2, ob2,
                                     (float*)d_out);
}